// Round 3
// baseline (224.262 us; speedup 1.0000x reference)
//
#include <hip/hip_runtime.h>

// out[s,a] = values[index[s,a]]
// index: 16384*2048 int32 (128 MiB), values: 100 fp32 (400 B), out: fp32 (128 MiB)
// Irreducible kernel traffic: 268.4 MB. Timed iteration = 2 harness fills
// (2x536.9 MB, ~160 us, untouchable) + kernel (~58 us @ ~4.7 TB/s).
// Aggregate iteration BW: 1342 MB / 218.9 us = 6.13 TB/s = 97.5% of the
// 6.29 TB/s measured copy ceiling.
//
// R8: last untested single-variable cache knob: drop nontemporal from the
// LOAD as well (R5 = nt/nt, R7 = nt-load/plain-store, both ~218). This makes
// the kernel's cache configuration identical to the 6.29 TB/s m13 copy
// microbenchmark (plain load + plain store). Theory: the nt bit on the read
// stream marks lines no-allocate in L2/L3 and defeats L2 read-combining /
// MC coalescing -- the only remaining structural difference from the copy
// bench on the read path. Everything else identical to R5 (1 int4/thread,
// block=1024, grid=8192, exact cover).
// Falsified so far: block granularity / wave count (R6 null), barrier
// convoying (R6 null), nt-store write-allocate policy (R7 null).

constexpr int VOCAB = 100;

typedef int   vint4   __attribute__((ext_vector_type(4)));
typedef float vfloat4 __attribute__((ext_vector_type(4)));

__global__ __launch_bounds__(1024) void gather_kernel(
    const vint4* __restrict__ idx4,
    const float* __restrict__ vals,
    vfloat4* __restrict__ out4)
{
    __shared__ float svals[VOCAB];
    if (threadIdx.x < VOCAB) svals[threadIdx.x] = vals[threadIdx.x];
    __syncthreads();

    const int t = blockIdx.x * blockDim.x + threadIdx.x;  // one int4 per thread

    vint4 v = idx4[t];                                    // plain cached load
    vfloat4 o = { svals[v.x], svals[v.y], svals[v.z], svals[v.w] };
    out4[t] = o;                                          // plain cached store
}

extern "C" void kernel_launch(void* const* d_in, const int* in_sizes, int n_in,
                              void* d_out, int out_size, void* d_ws, size_t ws_size,
                              hipStream_t stream) {
    const int*   idx  = (const int*)d_in[0];     // 16384*2048 int32
    const float* vals = (const float*)d_in[1];   // 100 fp32
    float*       out  = (float*)d_out;           // fp32

    int n  = in_sizes[0];                        // 33554432 (divisible by 4)
    int n4 = n / 4;                              // 8388608 = 8192 * 1024

    const int block = 1024;
    const int grid  = n4 / block;                // 8192 blocks, exact cover

    gather_kernel<<<grid, block, 0, stream>>>(
        (const vint4*)idx, vals, (vfloat4*)out);
}

// Round 4
// 218.616 us; speedup vs baseline: 1.0258x; 1.0258x over previous
//
#include <hip/hip_runtime.h>

// out[s,a] = values[index[s,a]]
// index: 16384*2048 int32 (128 MiB), values: 100 fp32 (400 B), out: fp32 (128 MiB)
//
// FINAL (R9 = revert to R5, the best-measured variant at 217.3 us).
//
// Roofline accounting: timed iteration = 2 harness re-poison fills
// (2 x 536.9 MB @ ~6.7 TB/s = ~160 us, untouchable) + this kernel
// (268.4 MB, ~57 us). Aggregate: 1342 MB / ~218 us = 6.16 TB/s = 98% of the
// 6.29 TB/s measured achievable HBM ceiling. At the roofline.
//
// Falsified single-variable hypotheses for the kernel-phase gap
// (4.7 TB/s effective vs 6.3 copy):
//   R6: 4 int4/thread + 2048 blocks (4x fewer prologues, 4x MLP)  -> null
//   R6: per-wave LDS tables, no __syncthreads (barrier convoying) -> null
//   R7: plain store (L3 write absorption)                          -> null
//   R8: plain load (L2 read-combining)                             -> null/-5us
// LDS/VALU/dispatch arithmetic all show >=4x headroom. The residual gap is a
// memory-system property of the dependent load->gather->store stream.

constexpr int VOCAB = 100;

typedef int   vint4   __attribute__((ext_vector_type(4)));
typedef float vfloat4 __attribute__((ext_vector_type(4)));

__global__ __launch_bounds__(1024) void gather_kernel(
    const vint4* __restrict__ idx4,
    const float* __restrict__ vals,
    vfloat4* __restrict__ out4)
{
    __shared__ float svals[VOCAB];
    if (threadIdx.x < VOCAB) svals[threadIdx.x] = vals[threadIdx.x];
    __syncthreads();

    const int t = blockIdx.x * blockDim.x + threadIdx.x;  // one int4 per thread

    vint4 v = __builtin_nontemporal_load(&idx4[t]);
    vfloat4 o = { svals[v.x], svals[v.y], svals[v.z], svals[v.w] };
    __builtin_nontemporal_store(o, &out4[t]);
}

extern "C" void kernel_launch(void* const* d_in, const int* in_sizes, int n_in,
                              void* d_out, int out_size, void* d_ws, size_t ws_size,
                              hipStream_t stream) {
    const int*   idx  = (const int*)d_in[0];     // 16384*2048 int32
    const float* vals = (const float*)d_in[1];   // 100 fp32
    float*       out  = (float*)d_out;           // fp32

    int n  = in_sizes[0];                        // 33554432 (divisible by 4)
    int n4 = n / 4;                              // 8388608 = 8192 * 1024

    const int block = 1024;
    const int grid  = n4 / block;                // 8192 blocks, exact cover

    gather_kernel<<<grid, block, 0, stream>>>(
        (const vint4*)idx, vals, (vfloat4*)out);
}